// Round 7
// baseline (949.967 us; speedup 1.0000x reference)
//
#include <hip/hip_runtime.h>
#include <hip/hip_bf16.h>
#include <stdint.h>

#define NCn 2000
#define NOn 100000
#define NEn 200000
#define ECOn 100000
#define EOCn 100000
#define EEOn 200000
#define EOEn 200000
#define NDST 402000   // dst segs: co@0(NO) oc@100000(NC) eo@102000(NO) oe@202000(NE)
#define NSRC 402000   // src segs: co@0(NC) oc@2000(NO) eo@102000(NE) oe@302000(NO)
#define NB1 1571      // ceil(402000/256)

typedef __bf16 bf16x8 __attribute__((ext_vector_type(8)));
typedef float f32x4 __attribute__((ext_vector_type(4)));
typedef unsigned short u16x8 __attribute__((ext_vector_type(8)));

__device__ inline unsigned short f2bf(float f) {
  return __builtin_bit_cast(unsigned short, (__bf16)f);
}
__device__ inline float bf2f(unsigned short u) {
  unsigned int x = ((unsigned int)u) << 16;
  return __builtin_bit_cast(float, x);
}
__device__ inline u16x8 cvt8(float4 a, float4 b) {
  u16x8 o;
  o[0] = f2bf(a.x); o[1] = f2bf(a.y); o[2] = f2bf(a.z); o[3] = f2bf(a.w);
  o[4] = f2bf(b.x); o[5] = f2bf(b.y); o[6] = f2bf(b.z); o[7] = f2bf(b.w);
  return o;
}
__device__ inline f32x4 mfma16(bf16x8 a, bf16x8 b, f32x4 c) {
  return __builtin_amdgcn_mfma_f32_16x16x32_bf16(a, b, c, 0, 0, 0);
}
__device__ inline bf16x8 g16(const unsigned short* p) {
  return __builtin_bit_cast(bf16x8, *(const u16x8*)p);
}
__device__ inline float sigm(float x) { return 1.f / (1.f + __expf(-x)); }

// XOR swizzle (ushort-index space): XOR col bits 3..5 with row&7 -> byte bits 4..6
#define XLI(r, c) ((r) * 128 + ((c) ^ (((r) & 7) << 3)))

// ---------------- CSR build ----------------
__global__ __launch_bounds__(256) void count2(const int* __restrict__ src,
                                              const int* __restrict__ dst, int n,
                                              int* __restrict__ cs, int* __restrict__ cd) {
  int i = blockIdx.x * 256 + threadIdx.x;
  if (i < n) {
    atomicAdd(&cs[src[i]], 1);
    atomicAdd(&cd[dst[i]], 1);
  }
}

__global__ __launch_bounds__(256) void scan1(const int* __restrict__ in, int* __restrict__ ex,
                                             int* __restrict__ bsum, int n) {
  __shared__ int s[256];
  int t = threadIdx.x, i = blockIdx.x * 256 + t;
  int v = (i < n) ? in[i] : 0;
  s[t] = v;
  for (int d = 1; d < 256; d <<= 1) {
    __syncthreads();
    int x = (t >= d) ? s[t - d] : 0;
    __syncthreads();
    s[t] += x;
  }
  __syncthreads();
  if (i < n) ex[i] = s[t] - v;
  if (t == 255) bsum[blockIdx.x] = s[255];
}

__global__ __launch_bounds__(256) void scan2(const int* __restrict__ bs, int* __restrict__ be, int nb) {
  __shared__ int s[256];
  __shared__ int carry;
  int t = threadIdx.x;
  if (t == 0) carry = 0;
  for (int t0 = 0; t0 < nb; t0 += 256) {
    int i = t0 + t;
    int v = (i < nb) ? bs[i] : 0;
    s[t] = v;
    for (int d = 1; d < 256; d <<= 1) {
      __syncthreads();
      int x = (t >= d) ? s[t - d] : 0;
      __syncthreads();
      s[t] += x;
    }
    __syncthreads();
    int c0 = carry;
    if (i < nb) be[i] = s[t] - v + c0;
    __syncthreads();
    if (t == 0) carry = c0 + s[255];
    __syncthreads();
  }
}

__global__ __launch_bounds__(256) void scan3(int* __restrict__ off, const int* __restrict__ be, int n) {
  int i = blockIdx.x * 256 + threadIdx.x;
  if (i < n) off[i] += be[blockIdx.x];
}

__global__ __launch_bounds__(256) void fillk(const int* __restrict__ src, const int* __restrict__ dst,
                                             int n, int* __restrict__ offseg, int* __restrict__ srcs) {
  int i = blockIdx.x * 256 + threadIdx.x;
  if (i < n) {
    int pos = atomicAdd(&offseg[dst[i]], 1);
    srcs[pos] = src[i];
  }
}

// ---------------- fused-weight precompute ----------------
// P[rel][k][j] (j<128: W_rel @ Wg1.T; j in [128,512): W_rel @ W_ih[j-128].T)
__global__ __launch_bounds__(256) void wgemmP(const float* __restrict__ Wco, const float* __restrict__ Woc,
                                              const float* __restrict__ Weo, const float* __restrict__ Woe,
                                              const float* __restrict__ GW, const float* __restrict__ WIH,
                                              float* __restrict__ P) {
  int idx = blockIdx.x * 256 + threadIdx.x;  // 4*128*512
  int rel = idx >> 16, r2 = idx & 65535, k = r2 >> 9, j = r2 & 511;
  const float* W = (rel == 0) ? Wco : (rel == 1) ? Woc : (rel == 2) ? Weo : Woe;
  const float* wr = &W[k * 128];
  const float* q = (j < 128) ? &GW[j * 384] : &WIH[(j - 128) * 128];
  float s = 0.f;
  for (int m = 0; m < 128; m += 4) {
    float4 a = *(const float4*)&wr[m];
    float4 b = *(const float4*)&q[m];
    s = fmaf(a.x, b.x, fmaf(a.y, b.y, fmaf(a.z, b.z, fmaf(a.w, b.w, s))));
  }
  P[idx] = s;
}

// colbias[type][512]: gate: gate_b + b@Wg1.T; r/z: b_ih+b_hh+b@Wih_c.T; n: b_ih+b@Wih_n.T
__global__ __launch_bounds__(256) void cbias(const float* __restrict__ GW, const float* __restrict__ WIH,
                                             const float* __restrict__ gate_b, const float* __restrict__ b_ih,
                                             const float* __restrict__ b_hh, const float* __restrict__ b_co,
                                             const float* __restrict__ b_oc, const float* __restrict__ b_eo,
                                             const float* __restrict__ b_oe, float* __restrict__ cb) {
  int idx = blockIdx.x * 256 + threadIdx.x;
  if (idx >= 1536) return;
  int type = idx / 512, j = idx & 511;
  float s = 0.f;
  for (int m = 0; m < 128; ++m) {
    float bm = (type == 0) ? b_oc[m] : (type == 1) ? (b_co[m] + b_eo[m]) : b_oe[m];
    float qm = (j < 128) ? GW[j * 384 + m] : WIH[(j - 128) * 128 + m];
    s = fmaf(bm, qm, s);
  }
  if (j < 128) s += gate_b[j];
  else {
    s += b_ih[j - 128];
    if (j < 384) s += b_hh[j - 128];  // b_hh folded for r,z only (n keeps it separate)
  }
  cb[idx] = s;
}

// ---------------- weight stream pack (fragment-ordered chunks) ----------------
// chunk = 16KB = [s:2][tn:8][lane:64][e:8] bf16, K=64 per chunk.
// type chunk bases: course 0..17, object 18..43, enroll 44..61.
// GRU stream slot order is r, n, z (kernel consumes r before n needs it, and
// nv replaces r in the same packed register array -> one live packed array).
// Per-slot order: 2x WHH chunks FIRST, then 2*nrel P-ih chunks.
__global__ __launch_bounds__(256) void packk(const float* __restrict__ P, const float* __restrict__ GW,
                                             const float* __restrict__ WHH, unsigned short* __restrict__ strm) {
  int g = blockIdx.x * 256 + threadIdx.x;  // 63488 groups of 8
  int chunk = g >> 10, within = g & 1023;
  int s = within >> 9, rem = within & 511, tn = rem >> 6, ln = rem & 63;
  int ml = ln & 15, kg = ln >> 4, col = tn * 16 + ml;
  int type, lc;
  if (chunk < 18) { type = 0; lc = chunk; }
  else if (chunk < 44) { type = 1; lc = chunk - 18; }
  else { type = 2; lc = chunk - 44; }
  int nrel = (type == 1) ? 2 : 1;
  int rel0 = (type == 0) ? 1 : (type == 1) ? 0 : 3;
  int rel1 = 2;  // object's second relation (eo)
  int gateN = 2 * nrel + 4;
  int mode, rel = 0, cc = 0, kb = 0;
  if (lc < 2 * nrel) { mode = 0; rel = (lc >> 1) ? rel1 : rel0; kb = (lc & 1) * 64; }
  else if (lc < 2 * nrel + 2) { mode = 1; kb = ((lc - 2 * nrel) & 1) * 64; }
  else if (lc < gateN) { mode = 2; kb = ((lc - 2 * nrel - 2) & 1) * 64; }
  else {
    int l2 = lc - gateN, per = 2 * nrel + 2;
    int slotc = l2 / per;
    cc = (slotc == 0) ? 0 : (slotc == 1) ? 2 : 1;  // stream slots: r, n, z
    int l3 = l2 % per;
    if (l3 < 2) { mode = 4; kb = (l3 & 1) * 64; }                       // WHH first
    else { mode = 3; rel = ((l3 - 2) >> 1) ? rel1 : rel0; kb = ((l3 - 2) & 1) * 64; }
  }
  u16x8 o;
#pragma unroll
  for (int e = 0; e < 8; ++e) {
    int k = kb + s * 32 + kg * 8 + e;
    float v;
    if (mode == 0) v = P[((rel * 128) + k) * 512 + col];
    else if (mode == 1) v = GW[col * 384 + 128 + k];
    else if (mode == 2) v = GW[col * 384 + 256 + k];
    else if (mode == 3) v = P[((rel * 128) + k) * 512 + 128 + cc * 128 + col];
    else v = WHH[(cc * 128 + col) * 128 + k];
    o[e] = f2bf(v);
  }
  *(u16x8*)&strm[(size_t)g * 8] = o;
}

// ---------------- gather aggregation into A-fragments ----------------
__device__ inline void gather_rel(const float* __restrict__ H, const int* __restrict__ cd,
                                  const int* __restrict__ offend, const int* __restrict__ cs,
                                  const int* __restrict__ srcs, int grow, int n, int kg,
                                  bf16x8 out[4]) {
  float ac[4][8];
#pragma unroll
  for (int a = 0; a < 4; ++a)
#pragma unroll
    for (int b = 0; b < 8; ++b) ac[a][b] = 0.f;
  if (grow < n) {
    int c = cd[grow];
    int end = offend[grow];
    for (int e = end - c; e < end; ++e) {
      int s = srcs[e];
      float sc = rsqrtf(fmaxf((float)cs[s], 1.f));
      const float4* hp = (const float4*)&H[(size_t)s * 128 + kg * 8];
#pragma unroll
      for (int ks = 0; ks < 4; ++ks) {
        float4 v0 = hp[ks * 8], v1 = hp[ks * 8 + 1];
        ac[ks][0] = fmaf(v0.x, sc, ac[ks][0]);
        ac[ks][1] = fmaf(v0.y, sc, ac[ks][1]);
        ac[ks][2] = fmaf(v0.z, sc, ac[ks][2]);
        ac[ks][3] = fmaf(v0.w, sc, ac[ks][3]);
        ac[ks][4] = fmaf(v1.x, sc, ac[ks][4]);
        ac[ks][5] = fmaf(v1.y, sc, ac[ks][5]);
        ac[ks][6] = fmaf(v1.z, sc, ac[ks][6]);
        ac[ks][7] = fmaf(v1.w, sc, ac[ks][7]);
      }
    }
    float iv = rsqrtf(fmaxf((float)c, 1.f));
#pragma unroll
    for (int ks = 0; ks < 4; ++ks)
#pragma unroll
      for (int b = 0; b < 8; ++b) ac[ks][b] *= iv;
  }
#pragma unroll
  for (int ks = 0; ks < 4; ++ks)
    out[ks] = __builtin_bit_cast(
        bf16x8, cvt8(make_float4(ac[ks][0], ac[ks][1], ac[ks][2], ac[ks][3]),
                     make_float4(ac[ks][4], ac[ks][5], ac[ks][6], ac[ks][7])));
}

// A-fragment from LDS: lane (ml,kg) needs cols kbase + kg*8 .. +7 of its row.
__device__ inline bf16x8 ldsA(const unsigned short* L, int arow, int kbase, int kg) {
  return __builtin_bit_cast(bf16x8, *(const u16x8*)&L[XLI(arow, kbase + kg * 8)]);
}

// ---------------- fused GNN layer kernel ----------------
// 128 nodes/block, 8 waves x 16 rows. Double-buffered fragment-ordered weight
// stream through LDS. LDS = 64KB; (512,4) caps total regs (VGPR+AGPR, unified
// file) at 128 -> 2 blocks/CU. GRU r->n->z ordering keeps only ONE packed
// gate array live at a time so the cap holds without spilling.
#define PHASE(P, A0, A1, ACC)                                                  \
  do {                                                                         \
    __syncthreads();                                                           \
    {                                                                          \
      int nb_ = (((P) + 1) & 1) * 8192;                                        \
      *(u16x8*)&wl[nb_ + tid * 8] = rA0;                                       \
      *(u16x8*)&wl[nb_ + 4096 + tid * 8] = rA1;                                \
      if ((P) + 2 < NCH) {                                                     \
        const unsigned short* sp_ = stream + (size_t)((P) + 2) * 8192;         \
        rA0 = *(const u16x8*)&sp_[tid * 8];                                    \
        rA1 = *(const u16x8*)&sp_[4096 + tid * 8];                             \
      }                                                                        \
    }                                                                          \
    {                                                                          \
      int cb_ = ((P) & 1) * 8192;                                              \
      _Pragma("unroll") for (int s_ = 0; s_ < 2; ++s_) {                       \
        bf16x8 a_ = (s_ ? (A1) : (A0));                                        \
        const unsigned short* wb_ = &wl[cb_ + s_ * 4096 + lane * 8];           \
        _Pragma("unroll") for (int tn_ = 0; tn_ < 8; ++tn_) {                  \
          bf16x8 b_ = g16(wb_ + tn_ * 512);                                    \
          ACC[tn_] = mfma16(a_, b_, ACC[tn_]);                                 \
        }                                                                      \
      }                                                                        \
    }                                                                          \
  } while (0)

template <int NREL>
__global__ __launch_bounds__(512, 4) void fuse_kernel(
    const float* __restrict__ H1, const float* __restrict__ H2,
    const float* __restrict__ Hs0, const int* __restrict__ cd0,
    const int* __restrict__ off0, const int* __restrict__ cs0,
    const float* __restrict__ Hs1, const int* __restrict__ cd1,
    const int* __restrict__ off1, const int* __restrict__ cs1,
    const int* __restrict__ srcs, const unsigned short* __restrict__ stream,
    const float* __restrict__ cb, const float* __restrict__ bhh,
    float* __restrict__ OUT, float* __restrict__ GOUT, int n) {
  constexpr int NCH = (NREL == 1) ? 18 : 26;
  __shared__ __align__(16) unsigned short A1l[16384];  // h1, later fused
  __shared__ __align__(16) unsigned short wl[16384];   // 2 x 16KB weight chunks
  int tid = threadIdx.x, lane = tid & 63, w = tid >> 6;
  int ml = lane & 15, kg = lane >> 4;
  int base = blockIdx.x * 128;
  int arow = 16 * w + ml;
  int grow = base + arow;

  // prefetch weight chunks 0 and 1
  u16x8 rA0 = *(const u16x8*)&stream[tid * 8];
  u16x8 rA1 = *(const u16x8*)&stream[4096 + tid * 8];
  u16x8 rB0 = *(const u16x8*)&stream[8192 + tid * 8];
  u16x8 rB1 = *(const u16x8*)&stream[12288 + tid * 8];

  // stage h1 tile (bf16, swizzled)
  for (int i = tid * 8; i < 16384; i += 4096) {
    int row = i >> 7, c = i & 127;
    int r = base + row;
    u16x8 o1 = {0, 0, 0, 0, 0, 0, 0, 0};
    if (r < n) {
      const float4* p1 = (const float4*)&H1[(size_t)r * 128 + c];
      o1 = cvt8(p1[0], p1[1]);
    }
    *(u16x8*)&A1l[XLI(row, c)] = o1;
  }

  // preload h2 A-fragments straight from global (die after gate GEMM)
  bf16x8 h2f[4];
#pragma unroll
  for (int q = 0; q < 4; ++q) {
    u16x8 o = {0, 0, 0, 0, 0, 0, 0, 0};
    if (grow < n) {
      const float* h2r = &H2[(size_t)grow * 128 + q * 32 + kg * 8];
      float4 a0 = *(const float4*)&h2r[0];
      float4 a1 = *(const float4*)&h2r[4];
      o = cvt8(a0, a1);
    }
    h2f[q] = __builtin_bit_cast(bf16x8, o);
  }

  // gather-aggregate neighbor features directly into MFMA A-fragments
  bf16x8 agg0[4], agg1[4];
  gather_rel(Hs0, cd0, off0, cs0, srcs, grow, n, kg, agg0);
  if (NREL == 2) gather_rel(Hs1, cd1, off1, cs1, srcs, grow, n, kg, agg1);

  // commit chunk 0 to wl buf0
  *(u16x8*)&wl[tid * 8] = rA0;
  *(u16x8*)&wl[4096 + tid * 8] = rA1;
  rA0 = rB0;
  rA1 = rB1;

  // ---- gate GEMM ----
  f32x4 accg[8] = {};
  if constexpr (NREL == 1) {
    PHASE(0, agg0[0], agg0[1], accg);
    PHASE(1, agg0[2], agg0[3], accg);
    PHASE(2, ldsA(A1l, arow, 0, kg), ldsA(A1l, arow, 32, kg), accg);
    PHASE(3, ldsA(A1l, arow, 64, kg), ldsA(A1l, arow, 96, kg), accg);
    PHASE(4, h2f[0], h2f[1], accg);
    PHASE(5, h2f[2], h2f[3], accg);
  } else {
    PHASE(0, agg0[0], agg0[1], accg);
    PHASE(1, agg0[2], agg0[3], accg);
    PHASE(2, agg1[0], agg1[1], accg);
    PHASE(3, agg1[2], agg1[3], accg);
    PHASE(4, ldsA(A1l, arow, 0, kg), ldsA(A1l, arow, 32, kg), accg);
    PHASE(5, ldsA(A1l, arow, 64, kg), ldsA(A1l, arow, 96, kg), accg);
    PHASE(6, h2f[0], h2f[1], accg);
    PHASE(7, h2f[2], h2f[3], accg);
  }

  // ---- gate epilogue: g, fused (fused overwrites A1l); h2 re-read 64B-coalesced ----
#pragma unroll
  for (int tn = 0; tn < 8; ++tn) {
    int col = tn * 16 + ml;
    float cbv = cb[col];
#pragma unroll
    for (int e = 0; e < 4; ++e) {
      int lrow = 16 * w + kg * 4 + e;
      int node = base + lrow;
      float gv = sigm(accg[tn][e] + cbv);
      float h1v = bf2f(A1l[XLI(lrow, col)]);
      float h2v = 0.f;
      if (node < n) h2v = bf2f(f2bf(H2[(size_t)node * 128 + col]));
      float fu = fmaf(gv, h1v - h2v, h2v);
      A1l[XLI(lrow, col)] = f2bf(fu);
      if (node < n) GOUT[(size_t)node * 128 + col] = gv;
    }
  }

  // ---- GRU slots in stream order r, n, z. WHH phases first, then ih phases.
  // Slot n folds r mid-chunk (r dies), then nv overwrites the same packed array,
  // slot z consumes nv -> exactly one packed 16-reg array live at any time.
  constexpr int GB = (NREL == 1) ? 6 : 8;
  constexpr int CPC = (NREL == 1) ? 4 : 6;
  unsigned int gp[16];  // packed gates: holds r, then nv
#pragma unroll
  for (int s = 0; s < 3; ++s) {
    int pb = GB + s * CPC;
    f32x4 acc[8] = {};
    PHASE(pb + 0, ldsA(A1l, arow, 0, kg), ldsA(A1l, arow, 32, kg), acc);
    PHASE(pb + 1, ldsA(A1l, arow, 64, kg), ldsA(A1l, arow, 96, kg), acc);
    if (s == 1) {
      // acc = gh_n partial; fold r and biases: acc <- cbn + r*(acc+bh)
#pragma unroll
      for (int tn = 0; tn < 8; ++tn) {
        int col = tn * 16 + ml;
        float cbn = cb[384 + col];
        float bh = bhh[256 + col];
#pragma unroll
        for (int e = 0; e < 4; ++e) {
          float rv = bf2f((unsigned short)(gp[tn * 2 + (e >> 1)] >> ((e & 1) * 16)));
          acc[tn][e] = fmaf(rv, acc[tn][e] + bh, cbn);
        }
      }
    }
    PHASE(pb + 2, agg0[0], agg0[1], acc);
    PHASE(pb + 3, agg0[2], agg0[3], acc);
    if constexpr (NREL == 2) {
      PHASE(pb + 4, agg1[0], agg1[1], acc);
      PHASE(pb + 5, agg1[2], agg1[3], acc);
    }
    if (s == 0) {  // r gate -> packed
#pragma unroll
      for (int tn = 0; tn < 8; ++tn) {
        int col = tn * 16 + ml;
        float cbc = cb[128 + col];
        gp[tn * 2] = (unsigned)f2bf(sigm(acc[tn][0] + cbc)) |
                     ((unsigned)f2bf(sigm(acc[tn][1] + cbc)) << 16);
        gp[tn * 2 + 1] = (unsigned)f2bf(sigm(acc[tn][2] + cbc)) |
                         ((unsigned)f2bf(sigm(acc[tn][3] + cbc)) << 16);
      }
    } else if (s == 1) {  // n: nv = tanh(acc) -> packed (overwrites r)
#pragma unroll
      for (int tn = 0; tn < 8; ++tn) {
        unsigned p0 = 0, p1 = 0;
#pragma unroll
        for (int e = 0; e < 4; ++e) {
          float x = fminf(fmaxf(acc[tn][e], -15.f), 15.f);
          float ex = __expf(2.f * x);
          float nv = (ex - 1.f) / (ex + 1.f);
          unsigned h = (unsigned)f2bf(nv);
          if (e == 0) p0 = h;
          else if (e == 1) p0 |= h << 16;
          else if (e == 2) p1 = h;
          else p1 |= h << 16;
        }
        gp[tn * 2] = p0;
        gp[tn * 2 + 1] = p1;
      }
    } else {  // z gate + output
#pragma unroll
      for (int tn = 0; tn < 8; ++tn) {
        int col = tn * 16 + ml;
        float cbz = cb[256 + col];
#pragma unroll
        for (int e = 0; e < 4; ++e) {
          int lrow = 16 * w + kg * 4 + e;
          float zv = sigm(acc[tn][e] + cbz);
          float nv = bf2f((unsigned short)(gp[tn * 2 + (e >> 1)] >> ((e & 1) * 16)));
          float fu = bf2f(A1l[XLI(lrow, col)]);
          float ht = fmaf(zv, fu - nv, nv);
          ht = fmaxf(ht, 0.f);
          int node = base + lrow;
          if (node < n) OUT[(size_t)node * 128 + col] = ht;
        }
      }
    }
  }
}

extern "C" void kernel_launch(void* const* d_in, const int* in_sizes, int n_in,
                              void* d_out, int out_size, void* d_ws, size_t ws_size,
                              hipStream_t stream) {
  const float* h1_course = (const float*)d_in[3];
  const float* h1_object = (const float*)d_in[4];
  const float* h1_enroll = (const float*)d_in[5];
  const float* h2_course = (const float*)d_in[6];
  const float* h2_object = (const float*)d_in[7];
  const float* h2_enroll = (const float*)d_in[8];
  const float* h_course = (const float*)d_in[0];
  const float* h_object = (const float*)d_in[1];
  const float* h_enroll = (const float*)d_in[2];
  const int* src_co = (const int*)d_in[9];
  const int* dst_co = (const int*)d_in[10];
  const int* src_oc = (const int*)d_in[11];
  const int* dst_oc = (const int*)d_in[12];
  const int* src_eo = (const int*)d_in[13];
  const int* dst_eo = (const int*)d_in[14];
  const int* src_oe = (const int*)d_in[15];
  const int* dst_oe = (const int*)d_in[16];
  const float* W_co = (const float*)d_in[17];
  const float* b_co = (const float*)d_in[18];
  const float* W_oc = (const float*)d_in[19];
  const float* b_oc = (const float*)d_in[20];
  const float* W_eo = (const float*)d_in[21];
  const float* b_eo = (const float*)d_in[22];
  const float* W_oe = (const float*)d_in[23];
  const float* b_oe = (const float*)d_in[24];
  const float* gate_W = (const float*)d_in[25];
  const float* gate_b = (const float*)d_in[26];
  const float* W_ih = (const float*)d_in[27];
  const float* W_hh = (const float*)d_in[28];
  const float* b_ih = (const float*)d_in[29];
  const float* b_hh = (const float*)d_in[30];

  float* out = (float*)d_out;
  float* out_c = out;
  float* out_o = out + (size_t)NCn * 128;
  float* out_e = out + (size_t)(NCn + NOn) * 128;
  float* g_c = out + (size_t)(NCn + NOn + NEn) * 128;
  float* g_o = g_c + (size_t)NCn * 128;
  float* g_e = g_o + (size_t)NOn * 128;

  // ws layout (assumes ws_size >= ~9.4 MB)
  char* wsb = (char*)d_ws;
  int* CNT_DST = (int*)(wsb + 0);            // 402000
  int* CNT_SRC = (int*)(wsb + 1608000);      // 402000
  int* OFF = (int*)(wsb + 3216000);          // 402000
  int* SRCS = (int*)(wsb + 4824000);         // 600000
  int* BSUM = (int*)(wsb + 7224000);         // 1600
  int* BEXC = (int*)(wsb + 7230400);         // 1600
  float* P = (float*)(wsb + 7236800);        // 262144
  float* CBv = (float*)(wsb + 8285376);      // 1536
  unsigned short* STRM = (unsigned short*)(wsb + 8291520);  // 507904

  hipMemsetAsync(CNT_DST, 0, 804000 * sizeof(int), stream);

  count2<<<(ECOn + 255) / 256, 256, 0, stream>>>(src_co, dst_co, ECOn, CNT_SRC + 0, CNT_DST + 0);
  count2<<<(EOCn + 255) / 256, 256, 0, stream>>>(src_oc, dst_oc, EOCn, CNT_SRC + 2000, CNT_DST + 100000);
  count2<<<(EEOn + 255) / 256, 256, 0, stream>>>(src_eo, dst_eo, EEOn, CNT_SRC + 102000, CNT_DST + 102000);
  count2<<<(EOEn + 255) / 256, 256, 0, stream>>>(src_oe, dst_oe, EOEn, CNT_SRC + 302000, CNT_DST + 202000);

  scan1<<<NB1, 256, 0, stream>>>(CNT_DST, OFF, BSUM, NDST);
  scan2<<<1, 256, 0, stream>>>(BSUM, BEXC, NB1);
  scan3<<<NB1, 256, 0, stream>>>(OFF, BEXC, NDST);

  fillk<<<(ECOn + 255) / 256, 256, 0, stream>>>(src_co, dst_co, ECOn, OFF + 0, SRCS);
  fillk<<<(EOCn + 255) / 256, 256, 0, stream>>>(src_oc, dst_oc, EOCn, OFF + 100000, SRCS);
  fillk<<<(EEOn + 255) / 256, 256, 0, stream>>>(src_eo, dst_eo, EEOn, OFF + 102000, SRCS);
  fillk<<<(EOEn + 255) / 256, 256, 0, stream>>>(src_oe, dst_oe, EOEn, OFF + 202000, SRCS);

  wgemmP<<<1024, 256, 0, stream>>>(W_co, W_oc, W_eo, W_oe, gate_W, W_ih, P);
  cbias<<<6, 256, 0, stream>>>(gate_W, W_ih, gate_b, b_ih, b_hh, b_co, b_oc, b_eo, b_oe, CBv);
  packk<<<248, 256, 0, stream>>>(P, gate_W, W_hh, STRM);

  // enroll (rel oe: dst seg 202000, src seg 302000, Hsrc = h_object)
  fuse_kernel<1><<<(NEn + 127) / 128, 512, 0, stream>>>(
      h1_enroll, h2_enroll, h_object, CNT_DST + 202000, OFF + 202000, CNT_SRC + 302000,
      nullptr, nullptr, nullptr, nullptr, SRCS, STRM + (size_t)44 * 8192, CBv + 1024, b_hh,
      out_e, g_e, NEn);
  // object (rel co: dst 0, src 0 (h_course); rel eo: dst 102000, src 102000 (h_enroll))
  fuse_kernel<2><<<(NOn + 127) / 128, 512, 0, stream>>>(
      h1_object, h2_object, h_course, CNT_DST + 0, OFF + 0, CNT_SRC + 0,
      h_enroll, CNT_DST + 102000, OFF + 102000, CNT_SRC + 102000, SRCS,
      STRM + (size_t)18 * 8192, CBv + 512, b_hh, out_o, g_o, NOn);
  // course (rel oc: dst seg 100000, src seg 2000, Hsrc = h_object)
  fuse_kernel<1><<<(NCn + 127) / 128, 512, 0, stream>>>(
      h1_course, h2_course, h_object, CNT_DST + 100000, OFF + 100000, CNT_SRC + 2000,
      nullptr, nullptr, nullptr, nullptr, SRCS, STRM + 0, CBv + 0, b_hh,
      out_c, g_c, NCn);
}

// Round 8
// 875.916 us; speedup vs baseline: 1.0845x; 1.0845x over previous
//
#include <hip/hip_runtime.h>
#include <hip/hip_bf16.h>
#include <stdint.h>

#define NCn 2000
#define NOn 100000
#define NEn 200000
#define ECOn 100000
#define EOCn 100000
#define EEOn 200000
#define EOEn 200000
#define NDST 402000   // dst segs: co@0(NO) oc@100000(NC) eo@102000(NO) oe@202000(NE)
#define NB1 1571      // ceil(402000/256)

typedef __bf16 bf16x8 __attribute__((ext_vector_type(8)));
typedef float f32x4 __attribute__((ext_vector_type(4)));
typedef unsigned short u16x8 __attribute__((ext_vector_type(8)));

__device__ inline unsigned short f2bf(float f) {
  return __builtin_bit_cast(unsigned short, (__bf16)f);
}
__device__ inline float bf2f(unsigned short u) {
  unsigned int x = ((unsigned int)u) << 16;
  return __builtin_bit_cast(float, x);
}
__device__ inline u16x8 cvt8(float4 a, float4 b) {
  u16x8 o;
  o[0] = f2bf(a.x); o[1] = f2bf(a.y); o[2] = f2bf(a.z); o[3] = f2bf(a.w);
  o[4] = f2bf(b.x); o[5] = f2bf(b.y); o[6] = f2bf(b.z); o[7] = f2bf(b.w);
  return o;
}
__device__ inline f32x4 mfma16(bf16x8 a, bf16x8 b, f32x4 c) {
  return __builtin_amdgcn_mfma_f32_16x16x32_bf16(a, b, c, 0, 0, 0);
}
__device__ inline bf16x8 g16(const unsigned short* p) {
  return __builtin_bit_cast(bf16x8, *(const u16x8*)p);
}
__device__ inline float sigm(float x) { return 1.f / (1.f + __expf(-x)); }

// XOR swizzle (ushort-index space) for A1l only
#define XLI(r, c) ((r) * 128 + ((c) ^ (((r) & 7) << 3)))

// ---------------- CSR build ----------------
__global__ __launch_bounds__(256) void count2(const int* __restrict__ src,
                                              const int* __restrict__ dst, int n,
                                              int* __restrict__ cs, int* __restrict__ cd) {
  int i = blockIdx.x * 256 + threadIdx.x;
  if (i < n) {
    atomicAdd(&cs[src[i]], 1);
    atomicAdd(&cd[dst[i]], 1);
  }
}

__global__ __launch_bounds__(256) void scan1(const int* __restrict__ in, int* __restrict__ ex,
                                             int* __restrict__ bsum, int n) {
  __shared__ int s[256];
  int t = threadIdx.x, i = blockIdx.x * 256 + t;
  int v = (i < n) ? in[i] : 0;
  s[t] = v;
  for (int d = 1; d < 256; d <<= 1) {
    __syncthreads();
    int x = (t >= d) ? s[t - d] : 0;
    __syncthreads();
    s[t] += x;
  }
  __syncthreads();
  if (i < n) ex[i] = s[t] - v;
  if (t == 255) bsum[blockIdx.x] = s[255];
}

__global__ __launch_bounds__(256) void scan2(const int* __restrict__ bs, int* __restrict__ be, int nb) {
  __shared__ int s[256];
  __shared__ int carry;
  int t = threadIdx.x;
  if (t == 0) carry = 0;
  for (int t0 = 0; t0 < nb; t0 += 256) {
    int i = t0 + t;
    int v = (i < nb) ? bs[i] : 0;
    s[t] = v;
    for (int d = 1; d < 256; d <<= 1) {
      __syncthreads();
      int x = (t >= d) ? s[t - d] : 0;
      __syncthreads();
      s[t] += x;
    }
    __syncthreads();
    int c0 = carry;
    if (i < nb) be[i] = s[t] - v + c0;
    __syncthreads();
    if (t == 0) carry = c0 + s[255];
    __syncthreads();
  }
}

__global__ __launch_bounds__(256) void scan3(int* __restrict__ off, const int* __restrict__ be, int n) {
  int i = blockIdx.x * 256 + threadIdx.x;
  if (i < n) off[i] += be[blockIdx.x];
}

__global__ __launch_bounds__(256) void fillk(const int* __restrict__ src, const int* __restrict__ dst,
                                             int n, int* __restrict__ offseg, int* __restrict__ srcs) {
  int i = blockIdx.x * 256 + threadIdx.x;
  if (i < n) {
    int pos = atomicAdd(&offseg[dst[i]], 1);
    srcs[pos] = src[i];
  }
}

// ---------------- fused-weight precompute ----------------
// P[rel][k][j] (j<128: W_rel @ Wg1.T; j in [128,512): W_rel @ W_ih[j-128].T)
__global__ __launch_bounds__(256) void wgemmP(const float* __restrict__ Wco, const float* __restrict__ Woc,
                                              const float* __restrict__ Weo, const float* __restrict__ Woe,
                                              const float* __restrict__ GW, const float* __restrict__ WIH,
                                              float* __restrict__ P) {
  int idx = blockIdx.x * 256 + threadIdx.x;  // 4*128*512
  int rel = idx >> 16, r2 = idx & 65535, k = r2 >> 9, j = r2 & 511;
  const float* W = (rel == 0) ? Wco : (rel == 1) ? Woc : (rel == 2) ? Weo : Woe;
  const float* wr = &W[k * 128];
  const float* q = (j < 128) ? &GW[j * 384] : &WIH[(j - 128) * 128];
  float s = 0.f;
  for (int m = 0; m < 128; m += 4) {
    float4 a = *(const float4*)&wr[m];
    float4 b = *(const float4*)&q[m];
    s = fmaf(a.x, b.x, fmaf(a.y, b.y, fmaf(a.z, b.z, fmaf(a.w, b.w, s))));
  }
  P[idx] = s;
}

// colbias[type][512]: gate: gate_b + b@Wg1.T; r/z: b_ih+b_hh+b@Wih_c.T; n: b_ih+b@Wih_n.T
__global__ __launch_bounds__(256) void cbias(const float* __restrict__ GW, const float* __restrict__ WIH,
                                             const float* __restrict__ gate_b, const float* __restrict__ b_ih,
                                             const float* __restrict__ b_hh, const float* __restrict__ b_co,
                                             const float* __restrict__ b_oc, const float* __restrict__ b_eo,
                                             const float* __restrict__ b_oe, float* __restrict__ cb) {
  int idx = blockIdx.x * 256 + threadIdx.x;
  if (idx >= 1536) return;
  int type = idx / 512, j = idx & 511;
  float s = 0.f;
  for (int m = 0; m < 128; ++m) {
    float bm = (type == 0) ? b_oc[m] : (type == 1) ? (b_co[m] + b_eo[m]) : b_oe[m];
    float qm = (j < 128) ? GW[j * 384 + m] : WIH[(j - 128) * 128 + m];
    s = fmaf(bm, qm, s);
  }
  if (j < 128) s += gate_b[j];
  else {
    s += b_ih[j - 128];
    if (j < 384) s += b_hh[j - 128];  // b_hh folded for r,z only (n keeps it separate)
  }
  cb[idx] = s;
}

// ---------------- weight stream pack: K=128 chunks (32KB each) ----------------
// chunk layout (ushorts): [s4:4][tn:8][lane:64][e:8]  (16384 ushorts)
// chunk sequence per type (phase order in fuse_kernel):
//  nrel=1 (course rel=oc / enroll rel=oe), 9 chunks:
//    PA, G1(h1), G2(h2), WHH_r, PI_r, WHH_n, PI_n, WHH_z, PI_z
//  nrel=2 (object), 13 chunks:
//    PA_co, PA_eo, G1, G2, WHH_r, PI_r_co, PI_r_eo, WHH_n, PI_n_co, PI_n_eo,
//    WHH_z, PI_z_co, PI_z_eo
// type bases (chunks): course 0, object 9, enroll 22. Total 31 chunks.
__global__ __launch_bounds__(256) void packk(const float* __restrict__ P, const float* __restrict__ GW,
                                             const float* __restrict__ WHH, unsigned short* __restrict__ strm) {
  int g = blockIdx.x * 256 + threadIdx.x;  // 63488 groups of 8 ushorts
  if (g >= 63488) return;
  int chunk = g >> 11, within = g & 2047;
  int ln = within & 63, tn = (within >> 6) & 7, s4 = within >> 9;
  int ml = ln & 15, kg = ln >> 4, col = tn * 16 + ml;
  int type, lc;
  if (chunk < 9) { type = 0; lc = chunk; }
  else if (chunk < 22) { type = 1; lc = chunk - 9; }
  else { type = 2; lc = chunk - 22; }
  int mode, rel = 0, cc = 0;
  if (type != 1) {
    rel = (type == 0) ? 1 : 3;  // oc / oe
    if (lc == 0) mode = 0;
    else if (lc == 1) mode = 1;
    else if (lc == 2) mode = 2;
    else {
      int l2 = lc - 3, slot = l2 >> 1;
      cc = (slot == 0) ? 0 : (slot == 1) ? 2 : 1;  // r, n, z
      mode = (l2 & 1) ? 3 : 4;                      // even WHH, odd PI
    }
  } else {
    if (lc == 0) { mode = 0; rel = 0; }
    else if (lc == 1) { mode = 0; rel = 2; }
    else if (lc == 2) mode = 1;
    else if (lc == 3) mode = 2;
    else {
      int l2 = lc - 4, slot = l2 / 3, l3 = l2 % 3;
      cc = (slot == 0) ? 0 : (slot == 1) ? 2 : 1;
      if (l3 == 0) mode = 4;
      else { mode = 3; rel = (l3 == 1) ? 0 : 2; }
    }
  }
  u16x8 o;
#pragma unroll
  for (int e = 0; e < 8; ++e) {
    int k = s4 * 32 + kg * 8 + e;
    float v;
    if (mode == 0) v = P[((rel * 128) + k) * 512 + col];
    else if (mode == 1) v = GW[col * 384 + 128 + k];
    else if (mode == 2) v = GW[col * 384 + 256 + k];
    else if (mode == 3) v = P[((rel * 128) + k) * 512 + 128 + cc * 128 + col];
    else v = WHH[(cc * 128 + col) * 128 + k];
    o[e] = f2bf(v);
  }
  *(u16x8*)&strm[(size_t)g * 8] = o;
}

// ---------------- gather aggregation into A-fragments ----------------
__device__ inline void gather_rel(const float* __restrict__ H, const int* __restrict__ cd,
                                  const int* __restrict__ offend, const int* __restrict__ cs,
                                  const int* __restrict__ srcs, int grow, int n, int kg,
                                  bf16x8 out[4]) {
  float ac[4][8];
#pragma unroll
  for (int a = 0; a < 4; ++a)
#pragma unroll
    for (int b = 0; b < 8; ++b) ac[a][b] = 0.f;
  if (grow < n) {
    int c = cd[grow];
    int end = offend[grow];
    for (int e = end - c; e < end; ++e) {
      int s = srcs[e];
      float sc = rsqrtf(fmaxf((float)cs[s], 1.f));
      const float4* hp = (const float4*)&H[(size_t)s * 128 + kg * 8];
#pragma unroll
      for (int ks = 0; ks < 4; ++ks) {
        float4 v0 = hp[ks * 8], v1 = hp[ks * 8 + 1];
        ac[ks][0] = fmaf(v0.x, sc, ac[ks][0]);
        ac[ks][1] = fmaf(v0.y, sc, ac[ks][1]);
        ac[ks][2] = fmaf(v0.z, sc, ac[ks][2]);
        ac[ks][3] = fmaf(v0.w, sc, ac[ks][3]);
        ac[ks][4] = fmaf(v1.x, sc, ac[ks][4]);
        ac[ks][5] = fmaf(v1.y, sc, ac[ks][5]);
        ac[ks][6] = fmaf(v1.z, sc, ac[ks][6]);
        ac[ks][7] = fmaf(v1.w, sc, ac[ks][7]);
      }
    }
    float iv = rsqrtf(fmaxf((float)c, 1.f));
#pragma unroll
    for (int ks = 0; ks < 4; ++ks)
#pragma unroll
      for (int b = 0; b < 8; ++b) ac[ks][b] *= iv;
  }
#pragma unroll
  for (int ks = 0; ks < 4; ++ks)
    out[ks] = __builtin_bit_cast(
        bf16x8, cvt8(make_float4(ac[ks][0], ac[ks][1], ac[ks][2], ac[ks][3]),
                     make_float4(ac[ks][4], ac[ks][5], ac[ks][6], ac[ks][7])));
}

// A-fragment from A1l: lane (ml,kg) reads cols kbase + kg*8 .. +7 of its row.
__device__ inline bf16x8 ldsA(const unsigned short* L, int arow, int kbase, int kg) {
  return __builtin_bit_cast(bf16x8, *(const u16x8*)&L[XLI(arow, kbase + kg * 8)]);
}

// ---------------- fused GNN layer kernel ----------------
// 128 nodes/block, 8 waves x 16 rows. Weight stream: K=128 chunks (32KB),
// ring-3 LDS staged via global_load_lds, issued 2 phases ahead, counted
// vmcnt + raw s_barrier (in-flight loads survive barriers). LDS = 128KB.

// issue one 32KB chunk: 4 glds x 16B per thread, lane-linear LDS dest
#define ISSUE(c)                                                               \
  do {                                                                         \
    const unsigned short* gs_ = stream + (size_t)(c) * 16384;                  \
    unsigned short* ld_ = &wl[((c) % 3) * 16384];                              \
    _Pragma("unroll") for (int j_ = 0; j_ < 4; ++j_) {                         \
      int o_ = j_ * 4096 + w * 512;                                            \
      __builtin_amdgcn_global_load_lds(                                        \
          (const __attribute__((address_space(1))) unsigned int*)(gs_ + o_ + lane * 8), \
          (__attribute__((address_space(3))) unsigned int*)(ld_ + o_), 16, 0, 0); \
    }                                                                          \
  } while (0)

#define PHTOP(p)                                                               \
  do {                                                                         \
    if ((p) == NPH - 1) asm volatile("s_waitcnt vmcnt(0)" ::: "memory");       \
    else asm volatile("s_waitcnt vmcnt(4)" ::: "memory");                      \
    __builtin_amdgcn_sched_barrier(0);                                         \
    __builtin_amdgcn_s_barrier();                                              \
    __builtin_amdgcn_sched_barrier(0);                                         \
    if ((p) + 2 < NPH) ISSUE((p) + 2);                                         \
    __builtin_amdgcn_sched_barrier(0);                                         \
  } while (0)

#define GEMMP(p, A0, A1, A2, A3, ACC)                                          \
  do {                                                                         \
    const unsigned short* wb_ = &wl[((p) % 3) * 16384] + lane * 8;             \
    bf16x8 aa_[4] = {A0, A1, A2, A3};                                          \
    _Pragma("unroll") for (int s4_ = 0; s4_ < 4; ++s4_) {                      \
      _Pragma("unroll") for (int tn_ = 0; tn_ < 8; ++tn_) {                    \
        ACC[tn_] = mfma16(aa_[s4_], g16(wb_ + (s4_ * 8 + tn_) * 512), ACC[tn_]); \
      }                                                                        \
    }                                                                          \
  } while (0)

#define PHASE4(p, A0, A1, A2, A3, ACC)                                         \
  do { PHTOP(p); GEMMP(p, A0, A1, A2, A3, ACC); } while (0)

template <int NREL>
__global__ __launch_bounds__(512, 2) void fuse_kernel(
    const float* __restrict__ H1, const float* __restrict__ H2,
    const float* __restrict__ Hs0, const int* __restrict__ cd0,
    const int* __restrict__ off0, const int* __restrict__ cs0,
    const float* __restrict__ Hs1, const int* __restrict__ cd1,
    const int* __restrict__ off1, const int* __restrict__ cs1,
    const int* __restrict__ srcs, const unsigned short* __restrict__ stream,
    const float* __restrict__ cb, const float* __restrict__ bhh,
    float* __restrict__ OUT, float* __restrict__ GOUT, int n) {
  constexpr int NPH = (NREL == 1) ? 9 : 13;
  __shared__ __align__(16) unsigned short A1l[16384];      // h1, later fused (32KB)
  __shared__ __align__(16) unsigned short wl[3 * 16384];   // ring-3 weight chunks (96KB)
  int tid = threadIdx.x, lane = tid & 63, w = tid >> 6;
  int ml = lane & 15, kg = lane >> 4;
  int base = blockIdx.x * 128;
  int arow = 16 * w + ml;
  int grow = base + arow;

  // stage h1 tile (bf16, swizzled)
  for (int i = tid * 8; i < 16384; i += 4096) {
    int row = i >> 7, c = i & 127;
    int r = base + row;
    u16x8 o1 = {0, 0, 0, 0, 0, 0, 0, 0};
    if (r < n) {
      const float4* p1 = (const float4*)&H1[(size_t)r * 128 + c];
      o1 = cvt8(p1[0], p1[1]);
    }
    *(u16x8*)&A1l[XLI(row, c)] = o1;
  }

  // preload h2 A-fragments straight from global (die after gate GEMM)
  bf16x8 h2f[4];
#pragma unroll
  for (int q = 0; q < 4; ++q) {
    u16x8 o = {0, 0, 0, 0, 0, 0, 0, 0};
    if (grow < n) {
      const float* h2r = &H2[(size_t)grow * 128 + q * 32 + kg * 8];
      float4 a0 = *(const float4*)&h2r[0];
      float4 a1 = *(const float4*)&h2r[4];
      o = cvt8(a0, a1);
    }
    h2f[q] = __builtin_bit_cast(bf16x8, o);
  }

  __syncthreads();  // A1l visible; drains all prologue vmem

  // start the weight pipeline, then overlap the gather under it
  ISSUE(0);
  ISSUE(1);

  bf16x8 agg0[4], agg1[4];
  gather_rel(Hs0, cd0, off0, cs0, srcs, grow, n, kg, agg0);
  if (NREL == 2) gather_rel(Hs1, cd1, off1, cs1, srcs, grow, n, kg, agg1);

  // ---- gate GEMM ----
  f32x4 accg[8] = {};
  if constexpr (NREL == 1) {
    PHASE4(0, agg0[0], agg0[1], agg0[2], agg0[3], accg);
    PHASE4(1, ldsA(A1l, arow, 0, kg), ldsA(A1l, arow, 32, kg),
              ldsA(A1l, arow, 64, kg), ldsA(A1l, arow, 96, kg), accg);
    PHASE4(2, h2f[0], h2f[1], h2f[2], h2f[3], accg);
  } else {
    PHASE4(0, agg0[0], agg0[1], agg0[2], agg0[3], accg);
    PHASE4(1, agg1[0], agg1[1], agg1[2], agg1[3], accg);
    PHASE4(2, ldsA(A1l, arow, 0, kg), ldsA(A1l, arow, 32, kg),
              ldsA(A1l, arow, 64, kg), ldsA(A1l, arow, 96, kg), accg);
    PHASE4(3, h2f[0], h2f[1], h2f[2], h2f[3], accg);
  }

  // ---- gate epilogue: g, fused (overwrites A1l own rows); h2 re-read coalesced ----
#pragma unroll
  for (int tn = 0; tn < 8; ++tn) {
    int col = tn * 16 + ml;
    float cbv = cb[col];
#pragma unroll
    for (int e = 0; e < 4; ++e) {
      int lrow = 16 * w + kg * 4 + e;
      int node = base + lrow;
      float gv = sigm(accg[tn][e] + cbv);
      float h1v = bf2f(A1l[XLI(lrow, col)]);
      float h2v = 0.f;
      if (node < n) h2v = bf2f(f2bf(H2[(size_t)node * 128 + col]));
      float fu = fmaf(gv, h1v - h2v, h2v);
      A1l[XLI(lrow, col)] = f2bf(fu);
      if (node < n) GOUT[(size_t)node * 128 + col] = gv;
    }
  }

  // ---- GRU slots in order r, n, z; per slot: WHH phase then PI(agg) phase(s).
  // Slot n folds r (and biases) between its WHH and PI phases so ONE accumulator
  // serves gh and gi; gp holds r then nv (one live packed array).
  constexpr int GB = (NREL == 1) ? 3 : 4;
  constexpr int CPC = (NREL == 1) ? 2 : 3;
  unsigned int gp[16];
#pragma unroll
  for (int s = 0; s < 3; ++s) {
    int pb = GB + s * CPC;
    f32x4 acc[8] = {};
    PHASE4(pb + 0, ldsA(A1l, arow, 0, kg), ldsA(A1l, arow, 32, kg),
                   ldsA(A1l, arow, 64, kg), ldsA(A1l, arow, 96, kg), acc);
    if (s == 1) {
      // acc = gh_n partial; fold r and biases: acc <- cbn + r*(acc+bh)
#pragma unroll
      for (int tn = 0; tn < 8; ++tn) {
        int col = tn * 16 + ml;
        float cbn = cb[384 + col];
        float bh = bhh[256 + col];
#pragma unroll
        for (int e = 0; e < 4; ++e) {
          float rv = bf2f((unsigned short)(gp[tn * 2 + (e >> 1)] >> ((e & 1) * 16)));
          acc[tn][e] = fmaf(rv, acc[tn][e] + bh, cbn);
        }
      }
    }
    PHASE4(pb + 1, agg0[0], agg0[1], agg0[2], agg0[3], acc);
    if constexpr (NREL == 2) {
      PHASE4(pb + 2, agg1[0], agg1[1], agg1[2], agg1[3], acc);
    }
    if (s == 0) {  // r -> packed
#pragma unroll
      for (int tn = 0; tn < 8; ++tn) {
        int col = tn * 16 + ml;
        float cbc = cb[128 + col];
        gp[tn * 2] = (unsigned)f2bf(sigm(acc[tn][0] + cbc)) |
                     ((unsigned)f2bf(sigm(acc[tn][1] + cbc)) << 16);
        gp[tn * 2 + 1] = (unsigned)f2bf(sigm(acc[tn][2] + cbc)) |
                         ((unsigned)f2bf(sigm(acc[tn][3] + cbc)) << 16);
      }
    } else if (s == 1) {  // nv = tanh(acc) -> packed (overwrites r)
#pragma unroll
      for (int tn = 0; tn < 8; ++tn) {
        unsigned p0 = 0, p1 = 0;
#pragma unroll
        for (int e = 0; e < 4; ++e) {
          float x = fminf(fmaxf(acc[tn][e], -15.f), 15.f);
          float ex = __expf(2.f * x);
          float nv = (ex - 1.f) / (ex + 1.f);
          unsigned h = (unsigned)f2bf(nv);
          if (e == 0) p0 = h;
          else if (e == 1) p0 |= h << 16;
          else if (e == 2) p1 = h;
          else p1 |= h << 16;
        }
        gp[tn * 2] = p0;
        gp[tn * 2 + 1] = p1;
      }
    } else {  // z + output
#pragma unroll
      for (int tn = 0; tn < 8; ++tn) {
        int col = tn * 16 + ml;
        float cbz = cb[256 + col];
#pragma unroll
        for (int e = 0; e < 4; ++e) {
          int lrow = 16 * w + kg * 4 + e;
          float zv = sigm(acc[tn][e] + cbz);
          float nv = bf2f((unsigned short)(gp[tn * 2 + (e >> 1)] >> ((e & 1) * 16)));
          float fu = bf2f(A1l[XLI(lrow, col)]);
          float ht = fmaf(zv, fu - nv, nv);
          ht = fmaxf(ht, 0.f);
          int node = base + lrow;
          if (node < n) OUT[(size_t)node * 128 + col] = ht;
        }
      }
    }
  }
}

extern "C" void kernel_launch(void* const* d_in, const int* in_sizes, int n_in,
                              void* d_out, int out_size, void* d_ws, size_t ws_size,
                              hipStream_t stream) {
  const float* h1_course = (const float*)d_in[3];
  const float* h1_object = (const float*)d_in[4];
  const float* h1_enroll = (const float*)d_in[5];
  const float* h2_course = (const float*)d_in[6];
  const float* h2_object = (const float*)d_in[7];
  const float* h2_enroll = (const float*)d_in[8];
  const float* h_course = (const float*)d_in[0];
  const float* h_object = (const float*)d_in[1];
  const float* h_enroll = (const float*)d_in[2];
  const int* src_co = (const int*)d_in[9];
  const int* dst_co = (const int*)d_in[10];
  const int* src_oc = (const int*)d_in[11];
  const int* dst_oc = (const int*)d_in[12];
  const int* src_eo = (const int*)d_in[13];
  const int* dst_eo = (const int*)d_in[14];
  const int* src_oe = (const int*)d_in[15];
  const int* dst_oe = (const int*)d_in[16];
  const float* W_co = (const float*)d_in[17];
  const float* b_co = (const float*)d_in[18];
  const float* W_oc = (const float*)d_in[19];
  const float* b_oc = (const float*)d_in[20];
  const float* W_eo = (const float*)d_in[21];
  const float* b_eo = (const float*)d_in[22];
  const float* W_oe = (const float*)d_in[23];
  const float* b_oe = (const float*)d_in[24];
  const float* gate_W = (const float*)d_in[25];
  const float* gate_b = (const float*)d_in[26];
  const float* W_ih = (const float*)d_in[27];
  const float* W_hh = (const float*)d_in[28];
  const float* b_ih = (const float*)d_in[29];
  const float* b_hh = (const float*)d_in[30];

  float* out = (float*)d_out;
  float* out_c = out;
  float* out_o = out + (size_t)NCn * 128;
  float* out_e = out + (size_t)(NCn + NOn) * 128;
  float* g_c = out + (size_t)(NCn + NOn + NEn) * 128;
  float* g_o = g_c + (size_t)NCn * 128;
  float* g_e = g_o + (size_t)NOn * 128;

  // ws layout (assumes ws_size >= ~9.4 MB, same as prior rounds)
  char* wsb = (char*)d_ws;
  int* CNT_DST = (int*)(wsb + 0);            // 402000
  int* CNT_SRC = (int*)(wsb + 1608000);      // 402000
  int* OFF = (int*)(wsb + 3216000);          // 402000
  int* SRCS = (int*)(wsb + 4824000);         // 600000
  int* BSUM = (int*)(wsb + 7224000);         // 1600
  int* BEXC = (int*)(wsb + 7230400);         // 1600
  float* P = (float*)(wsb + 7236800);        // 262144
  float* CBv = (float*)(wsb + 8285376);      // 1536
  unsigned short* STRM = (unsigned short*)(wsb + 8291520);  // 507904 ushorts (31 x 32KB)

  hipMemsetAsync(CNT_DST, 0, 804000 * sizeof(int), stream);

  count2<<<(ECOn + 255) / 256, 256, 0, stream>>>(src_co, dst_co, ECOn, CNT_SRC + 0, CNT_DST + 0);
  count2<<<(EOCn + 255) / 256, 256, 0, stream>>>(src_oc, dst_oc, EOCn, CNT_SRC + 2000, CNT_DST + 100000);
  count2<<<(EEOn + 255) / 256, 256, 0, stream>>>(src_eo, dst_eo, EEOn, CNT_SRC + 102000, CNT_DST + 102000);
  count2<<<(EOEn + 255) / 256, 256, 0, stream>>>(src_oe, dst_oe, EOEn, CNT_SRC + 302000, CNT_DST + 202000);

  scan1<<<NB1, 256, 0, stream>>>(CNT_DST, OFF, BSUM, NDST);
  scan2<<<1, 256, 0, stream>>>(BSUM, BEXC, NB1);
  scan3<<<NB1, 256, 0, stream>>>(OFF, BEXC, NDST);

  fillk<<<(ECOn + 255) / 256, 256, 0, stream>>>(src_co, dst_co, ECOn, OFF + 0, SRCS);
  fillk<<<(EOCn + 255) / 256, 256, 0, stream>>>(src_oc, dst_oc, EOCn, OFF + 100000, SRCS);
  fillk<<<(EEOn + 255) / 256, 256, 0, stream>>>(src_eo, dst_eo, EEOn, OFF + 102000, SRCS);
  fillk<<<(EOEn + 255) / 256, 256, 0, stream>>>(src_oe, dst_oe, EOEn, OFF + 202000, SRCS);

  wgemmP<<<1024, 256, 0, stream>>>(W_co, W_oc, W_eo, W_oe, gate_W, W_ih, P);
  cbias<<<6, 256, 0, stream>>>(gate_W, W_ih, gate_b, b_ih, b_hh, b_co, b_oc, b_eo, b_oe, CBv);
  packk<<<248, 256, 0, stream>>>(P, gate_W, W_hh, STRM);

  // enroll (rel oe: dst seg 202000, src seg 302000, Hsrc = h_object); chunks 22..30
  fuse_kernel<1><<<(NEn + 127) / 128, 512, 0, stream>>>(
      h1_enroll, h2_enroll, h_object, CNT_DST + 202000, OFF + 202000, CNT_SRC + 302000,
      nullptr, nullptr, nullptr, nullptr, SRCS, STRM + (size_t)22 * 16384, CBv + 1024, b_hh,
      out_e, g_e, NEn);
  // object (rel co: dst 0, src 0 (h_course); rel eo: dst 102000, src 102000 (h_enroll)); chunks 9..21
  fuse_kernel<2><<<(NOn + 127) / 128, 512, 0, stream>>>(
      h1_object, h2_object, h_course, CNT_DST + 0, OFF + 0, CNT_SRC + 0,
      h_enroll, CNT_DST + 102000, OFF + 102000, CNT_SRC + 102000, SRCS,
      STRM + (size_t)9 * 16384, CBv + 512, b_hh, out_o, g_o, NOn);
  // course (rel oc: dst seg 100000, src seg 2000, Hsrc = h_object); chunks 0..8
  fuse_kernel<1><<<(NCn + 127) / 128, 512, 0, stream>>>(
      h1_course, h2_course, h_object, CNT_DST + 100000, OFF + 100000, CNT_SRC + 2000,
      nullptr, nullptr, nullptr, nullptr, SRCS, STRM + 0, CBv + 0, b_hh,
      out_c, g_c, NCn);
}